// Round 7
// baseline (19483.939 us; speedup 1.0000x reference)
//
#include <hip/hip_runtime.h>
#include <math.h>

// ---------------------------------------------------------------------------
// QuantileCombinedModel — persistent-kernel LSTM encoder/decoder.
// R6: SEQLOCK DATAFLOW. No grid barriers, no flags, no fences, no drains.
// Every cross-WG datum (h0/h1/z) is an 8-byte (value,seq) pair written by its
// unique producer with a single atomic 8B store; consumers poll the pair until
// seq matches the producing phase. Validity is in-band -> handoff is ONE
// store-to-load flight instead of R5's 4 dependent round trips
// (drain-ack -> flag store -> flag poll -> data load).
//   seq(h0[t]) = 2t+2   (h0[-1]=0, prologue)   buffer slot t&3
//   seq(h1[t]) = 2t+3   (h1[-1]=1, prologue)   buffer slot t&3
//   seq(z[q])  = 2q+5   (produced in phase B of tick q+1)  slot q&3
// Depth-4 buffering is race-free: WG skew <= 1 tick (all-to-all dependence),
// and a writer reusing a slot (t+4) would require every tick-t reader done.
// Encoder reads x directly (constant input; no XT staging). ws = 1.25 MB.
// Arithmetic identical to R5 (passed, absmax 2.4e-4).
// ---------------------------------------------------------------------------

#define NW    128
#define NTHR  256

#define II 99
#define BB 64
#define TT 128
#define DD 325
#define QTOT 453
#define PPQ 9

#define SF_OFF 0
#define SB_OFF (BB*DD*II)            // 2059200
#define Y_OFF  (SB_OFF + BB*TT*II)   // 2870208

// ws float offsets — (value,seq) pair arrays
#define WS_H0P 0                     // [4 buf][256 unit][64 b][2] = 131072 f
#define WS_H1P 131072                // [4][256][64][2]
#define WS_ZBP 262144                // [4][128][64][2] = 65536 f   (1.25 MB total)

#define AGENT __HIP_MEMORY_SCOPE_AGENT

typedef float f4 __attribute__((ext_vector_type(4)));

__device__ __forceinline__ float sigm(float v){ return 1.0f/(1.0f+expf(-v)); }
__device__ __forceinline__ void st_wt(float* p, float v){ __hip_atomic_store(p, v, __ATOMIC_RELAXED, AGENT); }

// atomic 8B pair store: (value, seq) — single instruction, no tearing
__device__ __forceinline__ void stp(float* p, float v, unsigned s){
  unsigned long long u = ((unsigned long long)s << 32) | (unsigned long long)__float_as_uint(v);
  __hip_atomic_store((unsigned long long*)p, u, __ATOMIC_RELAXED, AGENT);
}

__device__ __forceinline__ void fma32(float acc[32], f4 w0, f4 w1, f4 hv) {
  float wr[8] = {w0.x,w0.y,w0.z,w0.w,w1.x,w1.y,w1.z,w1.w};
  #pragma unroll
  for (int g = 0; g < 8; ++g) {
    acc[(g<<2)+0] += wr[g]*hv.x;
    acc[(g<<2)+1] += wr[g]*hv.y;
    acc[(g<<2)+2] += wr[g]*hv.z;
    acc[(g<<2)+3] += wr[g]*hv.w;
  }
}

__global__ __launch_bounds__(NTHR, 1)
void qcm_kernel(const float* __restrict__ x,
                const float* __restrict__ Wih0, const float* __restrict__ Whh0, const float* __restrict__ b0,
                const float* __restrict__ Wih1, const float* __restrict__ Whh1, const float* __restrict__ b1,
                const float* __restrict__ Wlin, const float* __restrict__ blin,
                const float* __restrict__ Wp1,  const float* __restrict__ bp1,
                const float* __restrict__ Wp2,  const float* __restrict__ bp2,
                float* __restrict__ out, float* __restrict__ ws)
{
  // ---- LDS (~56 KB) ----
  __shared__ float sWih0[II*8];      // [k][g]
  __shared__ float sWhh0[2048];
  __shared__ float sWc  [2048];
  __shared__ float sWih1[2048];
  __shared__ float sWhh1[2048];
  __shared__ float sWlin[256];
  __shared__ float sWp1 [256];
  __shared__ float sWp2 [10*128];
  __shared__ float sGred[4*512];
  __shared__ float sGates[512];
  __shared__ float sHs[4*64];
  __shared__ float sHz[4*64];
  __shared__ float sYred[2][8];
  __shared__ float sB[48];           // 0..7 b0 | 8..15 b0c | 16..23 b1 | 24 blin 25 bp1 | 32..40 bp2

  float* H0P = ws + WS_H0P;
  float* H1P = ws + WS_H1P;
  float* ZBP = ws + WS_ZBP;

  const int wg  = (int)blockIdx.x;
  const int tid = (int)threadIdx.x;
  const int wv  = tid >> 6;
  const int ln  = tid & 63;
  const int rg  = ln >> 2;
  const int rb  = rg << 2;              // batch base (4 per thread)
  const int ks  = (wv << 2) | (ln & 3); // k-sub 0..15
  const int u0  = wg << 1;

  float c0 = 0.f, c1 = 0.f;

  // poll one 8-fragment chunk of a pair array until all seqs match exp
  auto poll8 = [&](const float* hb, unsigned exp, int c2, f4* hv) {
    bool ok;
    do {
      ok = true;
      #pragma unroll
      for (int j = 0; j < 8; ++j) {
        int k = ks + (((c2<<3) + j) << 4);
        const float* p = hb + (((size_t)(k<<6) + rb) << 1);
        unsigned long long a = __hip_atomic_load((const unsigned long long*)(p  ), __ATOMIC_RELAXED, AGENT);
        unsigned long long b2= __hip_atomic_load((const unsigned long long*)(p+2), __ATOMIC_RELAXED, AGENT);
        unsigned long long c2_=__hip_atomic_load((const unsigned long long*)(p+4), __ATOMIC_RELAXED, AGENT);
        unsigned long long d = __hip_atomic_load((const unsigned long long*)(p+6), __ATOMIC_RELAXED, AGENT);
        hv[j].x = __uint_as_float((unsigned)a);
        hv[j].y = __uint_as_float((unsigned)b2);
        hv[j].z = __uint_as_float((unsigned)c2_);
        hv[j].w = __uint_as_float((unsigned)d);
        ok = ok & ((unsigned)(a>>32)==exp) & ((unsigned)(b2>>32)==exp)
                & ((unsigned)(c2_>>32)==exp) & ((unsigned)(d>>32)==exp);
      }
      if (!ok) __builtin_amdgcn_s_sleep(1);
    } while (!ok);
  };

  // ======================= PROLOGUE =======================
  for (int idx = tid; idx < II*8; idx += NTHR) {
    int k = idx >> 3, g = idx & 7;
    int gate = ((g >> 1) << 8) + u0 + (g & 1);
    sWih0[idx] = Wih0[gate*II + k];
  }
  for (int idx = tid; idx < 2048; idx += NTHR) {
    int k = idx >> 3, g = idx & 7;
    int gate = ((g >> 1) << 8) + u0 + (g & 1);
    sWhh0[idx] = Whh0[(gate << 8) + k];
    sWih1[idx] = Wih1[(gate << 8) + k];
    sWhh1[idx] = Whh1[(gate << 8) + k];
  }
  sWlin[tid] = (wg < II) ? Wlin[wg*256 + tid] : 0.f;
  sWp1[tid]  = Wp1[wg*256 + tid];
  for (int idx = tid; idx < 1280; idx += NTHR) sWp2[idx] = (idx < 1152) ? Wp2[idx] : 0.f;
  if (tid < 8) {
    int gate = ((tid >> 1) << 8) + u0 + (tid & 1);
    sB[tid]      = b0[gate];
    sB[16 + tid] = b1[gate];
  }
  if (tid == 0) {
    sB[24] = (wg < II) ? blin[wg] : 0.f;
    sB[25] = bp1[wg];
  }
  if (tid < 9) sB[32 + tid] = bp2[tid];
  __syncthreads();
  // Wc slice: sWc[k*8+g] = sum_j Wih0[gate(g)][j] * Wlin[j][k]
  for (int idx = tid; idx < 2048; idx += NTHR) {
    int k = idx >> 3, g = idx & 7;
    float a = 0.f;
    for (int j = 0; j < II; ++j) a += sWih0[(j << 3) + g] * Wlin[(j << 8) + k];
    sWc[idx] = a;
  }
  if (tid < 8) {
    float a = 0.f;
    for (int j = 0; j < II; ++j) a += sWih0[(j << 3) + tid] * blin[j];
    sB[8 + tid] = sB[tid] + a;
  }
  // initial state: h0[-1]=0 seq 0, h1[-1]=0 seq 1, in slot (-1)&3 = 3
  if (tid < 128) {
    int uu = tid >> 6, r = tid & 63;
    stp(H0P + ((size_t)3 << 15) + ((((size_t)(u0+uu) << 6) + r) << 1), 0.f, 0u);
    stp(H1P + ((size_t)3 << 15) + ((((size_t)(u0+uu) << 6) + r) << 1), 0.f, 1u);
  }
  __syncthreads();

  const int bq = wg >> 1, pb = (wg & 1) ? 5 : 0;

  for (int ctr = 0; ctr <= 454; ++ctr) {
    // ========================= PHASE A (layer-0 step + yld head) =========================
    if (ctr <= 452) {
      float acc[32];
      #pragma unroll
      for (int q2 = 0; q2 < 32; ++q2) acc[q2] = 0.f;
      f4 hv[8];

      if (ctr < TT) {
        // encoder: Wih0 @ x_t  (direct, cached input) ...
        for (int m = 0; m < 7; ++m) {
          int k = ks + (m << 4);
          if (k < II) {
            f4 xv;
            xv.x = x[(size_t)(rb+0)*(TT*II) + ctr*II + k];
            xv.y = x[(size_t)(rb+1)*(TT*II) + ctr*II + k];
            xv.z = x[(size_t)(rb+2)*(TT*II) + ctr*II + k];
            xv.w = x[(size_t)(rb+3)*(TT*II) + ctr*II + k];
            fma32(acc, *(const f4*)(sWih0 + (k<<3)), *(const f4*)(sWih0 + (k<<3) + 4), xv);
          }
        }
        // ... + Whh0 @ h0[ctr-1]  (seq 2*ctr, slot (ctr-1)&3)
        const float* hb = H0P + ((size_t)((ctr-1)&3) << 15);
        const unsigned e0 = (unsigned)(2*ctr);
        for (int c2 = 0; c2 < 2; ++c2) {
          poll8(hb, e0, c2, hv);
          #pragma unroll
          for (int j = 0; j < 8; ++j) {
            int k = ks + (((c2<<3)+j) << 4);
            fma32(acc, *(const f4*)(sWhh0 + (k<<3)), *(const f4*)(sWhh0 + (k<<3) + 4), hv[j]);
          }
        }
      } else {
        // decoder: Whh0 @ h0[ctr-1]  (older, lands first) ...
        {
          const float* hb = H0P + ((size_t)((ctr-1)&3) << 15);
          const unsigned e0 = (unsigned)(2*ctr);
          for (int c2 = 0; c2 < 2; ++c2) {
            poll8(hb, e0, c2, hv);
            #pragma unroll
            for (int j = 0; j < 8; ++j) {
              int k = ks + (((c2<<3)+j) << 4);
              fma32(acc, *(const f4*)(sWhh0 + (k<<3)), *(const f4*)(sWhh0 + (k<<3) + 4), hv[j]);
            }
          }
        }
        // ... + Wc @ relu(h1[ctr-1])  (fresh from previous phase B)
        {
          const float* hb = H1P + ((size_t)((ctr-1)&3) << 15);
          const unsigned e1 = (unsigned)(2*ctr+1);
          for (int c2 = 0; c2 < 2; ++c2) {
            poll8(hb, e1, c2, hv);
            #pragma unroll
            for (int j = 0; j < 8; ++j) {
              int k = ks + (((c2<<3)+j) << 4);
              f4 h1v = hv[j];
              h1v.x = fmaxf(h1v.x, 0.f); h1v.y = fmaxf(h1v.y, 0.f);
              h1v.z = fmaxf(h1v.z, 0.f); h1v.w = fmaxf(h1v.w, 0.f);
              fma32(acc, *(const f4*)(sWc + (k<<3)), *(const f4*)(sWc + (k<<3) + 4), h1v);
            }
          }
        }
      }
      // gate partial reduce
      #pragma unroll
      for (int q2 = 0; q2 < 32; ++q2) {
        float v = acc[q2];
        v += __shfl_xor(v, 1, 64); v += __shfl_xor(v, 2, 64);
        acc[q2] = v;
      }
      if ((ln & 3) == 0) {
        #pragma unroll
        for (int g = 0; g < 8; ++g)
          *(float4*)(sGred + (wv << 9) + (g << 6) + rb) =
            make_float4(acc[(g<<2)], acc[(g<<2)+1], acc[(g<<2)+2], acc[(g<<2)+3]);
      }
      // yields head: poll z[q=ctr-2] pair (seq 2q+5)
      if (ctr >= 2 && tid < 128) {
        int q = ctr - 2;
        const unsigned ez = (unsigned)(2*q+5);
        const float* zp = ZBP + ((size_t)(q&3) << 14) + ((((size_t)tid << 6) + bq) << 1);
        unsigned long long u;
        for (;;) {
          u = __hip_atomic_load((const unsigned long long*)zp, __ATOMIC_RELAXED, AGENT);
          if ((unsigned)(u>>32) == ez) break;
          __builtin_amdgcn_s_sleep(1);
        }
        float zv = __uint_as_float((unsigned)u);
        float yp[5];
        #pragma unroll
        for (int p = 0; p < 5; ++p) yp[p] = zv * sWp2[((pb + p) << 7) + tid];
        #pragma unroll
        for (int p = 0; p < 5; ++p) {
          float v = yp[p];
          v += __shfl_xor(v,1,64); v += __shfl_xor(v,2,64); v += __shfl_xor(v,4,64);
          v += __shfl_xor(v,8,64); v += __shfl_xor(v,16,64); v += __shfl_xor(v,32,64);
          yp[p] = v;
        }
        if (ln == 0) {
          #pragma unroll
          for (int p = 0; p < 5; ++p) sYred[wv][p] = yp[p];
        }
      }
      __syncthreads();
      if (tid < 128) { // gate final sum + bias
        const int boff = (ctr < TT) ? 0 : 8;
        float4 a0 = *(const float4*)(sGred +    0 + (tid<<2));
        float4 a1 = *(const float4*)(sGred +  512 + (tid<<2));
        float4 a2 = *(const float4*)(sGred + 1024 + (tid<<2));
        float4 a3 = *(const float4*)(sGred + 1536 + (tid<<2));
        float bias = sB[boff + (tid >> 4)];
        float4 r;
        r.x = a0.x+a1.x+a2.x+a3.x + bias;
        r.y = a0.y+a1.y+a2.y+a3.y + bias;
        r.z = a0.z+a1.z+a2.z+a3.z + bias;
        r.w = a0.w+a1.w+a2.w+a3.w + bias;
        *(float4*)(sGates + (tid<<2)) = r;
      }
      __syncthreads();
      if (tid < 128) { // LSTM cell, layer 0 -> pair store seq 2*ctr+2, slot ctr&3
        int uu = tid >> 6, r = tid & 63;
        float i_ = sigm (sGates[( uu      << 6) + r]);
        float f_ = sigm (sGates[((2 + uu) << 6) + r]);
        float g_ = tanhf(sGates[((4 + uu) << 6) + r]);
        float o_ = sigm (sGates[((6 + uu) << 6) + r]);
        float c = f_*c0 + i_*g_;
        c0 = c;
        stp(H0P + ((size_t)(ctr&3) << 15) + ((((size_t)(u0+uu) << 6) + r) << 1),
            o_*tanhf(c), (unsigned)(2*ctr+2));
      }
      if (ctr >= 2 && tid >= 192 && tid < 197) {
        int p = tid - 192;
        if (pb + p < 9) {
          float y = sYred[0][p] + sYred[1][p] + sB[32 + pb + p];
          st_wt(&out[Y_OFF + ((size_t)bq*QTOT + (ctr - 2))*PPQ + pb + p], y);
        }
      }
    } else { // ctr = 453/454: yields head only
      if (tid < 128) {
        int q = ctr - 2;
        const unsigned ez = (unsigned)(2*q+5);
        const float* zp = ZBP + ((size_t)(q&3) << 14) + ((((size_t)tid << 6) + bq) << 1);
        unsigned long long u;
        for (;;) {
          u = __hip_atomic_load((const unsigned long long*)zp, __ATOMIC_RELAXED, AGENT);
          if ((unsigned)(u>>32) == ez) break;
          __builtin_amdgcn_s_sleep(1);
        }
        float zv = __uint_as_float((unsigned)u);
        float yp[5];
        #pragma unroll
        for (int p = 0; p < 5; ++p) yp[p] = zv * sWp2[((pb + p) << 7) + tid];
        #pragma unroll
        for (int p = 0; p < 5; ++p) {
          float v = yp[p];
          v += __shfl_xor(v,1,64); v += __shfl_xor(v,2,64); v += __shfl_xor(v,4,64);
          v += __shfl_xor(v,8,64); v += __shfl_xor(v,16,64); v += __shfl_xor(v,32,64);
          yp[p] = v;
        }
        if (ln == 0) {
          #pragma unroll
          for (int p = 0; p < 5; ++p) sYred[wv][p] = yp[p];
        }
      }
      __syncthreads();
      if (tid >= 192 && tid < 197) {
        int p = tid - 192;
        if (pb + p < 9) {
          float y = sYred[0][p] + sYred[1][p] + sB[32 + pb + p];
          st_wt(&out[Y_OFF + ((size_t)bq*QTOT + (ctr - 2))*PPQ + pb + p], y);
        }
      }
    }
    if (ctr == 454) break;

    // ========================= PHASE B (layer-1 step + sens/z heads) =========================
    {
      float ps[4] = {0,0,0,0}, pz[4] = {0,0,0,0};
      f4 hv[8];

      if (ctr <= 452) {
        float acc[32];
        #pragma unroll
        for (int q2 = 0; q2 < 32; ++q2) acc[q2] = 0.f;

        // Whh1 @ h1[ctr-1] + head partials (older data)
        {
          const float* hb = H1P + ((size_t)((ctr-1)&3) << 15);
          const unsigned e1 = (unsigned)(2*ctr+1);
          for (int c2 = 0; c2 < 2; ++c2) {
            poll8(hb, e1, c2, hv);
            #pragma unroll
            for (int j = 0; j < 8; ++j) {
              int k = ks + (((c2<<3)+j) << 4);
              f4 h1v = hv[j];
              fma32(acc, *(const f4*)(sWhh1 + (k<<3)), *(const f4*)(sWhh1 + (k<<3) + 4), h1v);
              float rx = fmaxf(h1v.x,0.f), ry = fmaxf(h1v.y,0.f), rz = fmaxf(h1v.z,0.f), rw = fmaxf(h1v.w,0.f);
              float wl = sWlin[k], wp = sWp1[k];
              ps[0] += rx*wl; ps[1] += ry*wl; ps[2] += rz*wl; ps[3] += rw*wl;
              pz[0] += rx*wp; pz[1] += ry*wp; pz[2] += rz*wp; pz[3] += rw*wp;
            }
          }
        }
        // Wih1 @ h0[ctr]  (fresh from this tick's phase A)
        {
          const float* hb = H0P + ((size_t)(ctr&3) << 15);
          const unsigned e0 = (unsigned)(2*ctr+2);
          for (int c2 = 0; c2 < 2; ++c2) {
            poll8(hb, e0, c2, hv);
            #pragma unroll
            for (int j = 0; j < 8; ++j) {
              int k = ks + (((c2<<3)+j) << 4);
              fma32(acc, *(const f4*)(sWih1 + (k<<3)), *(const f4*)(sWih1 + (k<<3) + 4), hv[j]);
            }
          }
        }
        #pragma unroll
        for (int q2 = 0; q2 < 32; ++q2) {
          float v = acc[q2];
          v += __shfl_xor(v, 1, 64); v += __shfl_xor(v, 2, 64);
          acc[q2] = v;
        }
        #pragma unroll
        for (int j = 0; j < 4; ++j) {
          float v = ps[j]; v += __shfl_xor(v,1,64); v += __shfl_xor(v,2,64); ps[j] = v;
          v = pz[j]; v += __shfl_xor(v,1,64); v += __shfl_xor(v,2,64); pz[j] = v;
        }
        if ((ln & 3) == 0) {
          #pragma unroll
          for (int g = 0; g < 8; ++g)
            *(float4*)(sGred + (wv << 9) + (g << 6) + rb) =
              make_float4(acc[(g<<2)], acc[(g<<2)+1], acc[(g<<2)+2], acc[(g<<2)+3]);
          *(float4*)(sHs + (wv << 6) + rb) = make_float4(ps[0],ps[1],ps[2],ps[3]);
          *(float4*)(sHz + (wv << 6) + rb) = make_float4(pz[0],pz[1],pz[2],pz[3]);
        }
        __syncthreads();
        if (tid < 128) {
          float4 a0 = *(const float4*)(sGred +    0 + (tid<<2));
          float4 a1 = *(const float4*)(sGred +  512 + (tid<<2));
          float4 a2 = *(const float4*)(sGred + 1024 + (tid<<2));
          float4 a3 = *(const float4*)(sGred + 1536 + (tid<<2));
          float bias = sB[16 + (tid >> 4)];
          float4 r;
          r.x = a0.x+a1.x+a2.x+a3.x + bias;
          r.y = a0.y+a1.y+a2.y+a3.y + bias;
          r.z = a0.z+a1.z+a2.z+a3.z + bias;
          r.w = a0.w+a1.w+a2.w+a3.w + bias;
          *(float4*)(sGates + (tid<<2)) = r;
        } else if (tid < 192 && ctr >= 1) { // sens/z finalize, q = ctr-1
          int b = tid - 128, q = ctr - 1;
          float s = sHs[b] + sHs[64+b] + sHs[128+b] + sHs[192+b] + sB[24];
          float z = fmaxf(sHz[b] + sHz[64+b] + sHz[128+b] + sHz[192+b] + sB[25], 0.f);
          if (wg < II) {
            size_t o = (q < TT) ? (SB_OFF + ((size_t)b*TT + q)*II + wg)
                                : (SF_OFF + ((size_t)b*DD + (q - TT))*II + wg);
            st_wt(&out[o], s);
          }
          stp(ZBP + ((size_t)(q&3) << 14) + ((((size_t)wg << 6) + b) << 1), z, (unsigned)(2*q+5));
        }
        __syncthreads();
        if (tid < 128) { // LSTM cell, layer 1 -> pair store seq 2*ctr+3, slot ctr&3
          int uu = tid >> 6, r = tid & 63;
          float i_ = sigm (sGates[( uu      << 6) + r]);
          float f_ = sigm (sGates[((2 + uu) << 6) + r]);
          float g_ = tanhf(sGates[((4 + uu) << 6) + r]);
          float o_ = sigm (sGates[((6 + uu) << 6) + r]);
          float c = f_*c1 + i_*g_;
          c1 = c;
          stp(H1P + ((size_t)(ctr&3) << 15) + ((((size_t)(u0+uu) << 6) + r) << 1),
              o_*tanhf(c), (unsigned)(2*ctr+3));
        }
      } else { // ctr == 453: heads only from h1[452]
        const float* hb = H1P + ((size_t)((ctr-1)&3) << 15);
        const unsigned e1 = (unsigned)(2*ctr+1);   // = 907 = seq(h1[452])
        for (int c2 = 0; c2 < 2; ++c2) {
          poll8(hb, e1, c2, hv);
          #pragma unroll
          for (int j = 0; j < 8; ++j) {
            int k = ks + (((c2<<3)+j) << 4);
            f4 h1v = hv[j];
            float rx = fmaxf(h1v.x,0.f), ry = fmaxf(h1v.y,0.f), rz = fmaxf(h1v.z,0.f), rw = fmaxf(h1v.w,0.f);
            float wl = sWlin[k], wp = sWp1[k];
            ps[0] += rx*wl; ps[1] += ry*wl; ps[2] += rz*wl; ps[3] += rw*wl;
            pz[0] += rx*wp; pz[1] += ry*wp; pz[2] += rz*wp; pz[3] += rw*wp;
          }
        }
        #pragma unroll
        for (int j = 0; j < 4; ++j) {
          float v = ps[j]; v += __shfl_xor(v,1,64); v += __shfl_xor(v,2,64); ps[j] = v;
          v = pz[j]; v += __shfl_xor(v,1,64); v += __shfl_xor(v,2,64); pz[j] = v;
        }
        if ((ln & 3) == 0) {
          *(float4*)(sHs + (wv << 6) + rb) = make_float4(ps[0],ps[1],ps[2],ps[3]);
          *(float4*)(sHz + (wv << 6) + rb) = make_float4(pz[0],pz[1],pz[2],pz[3]);
        }
        __syncthreads();
        if (tid >= 128 && tid < 192) {
          int b = tid - 128, q = ctr - 1;
          float s = sHs[b] + sHs[64+b] + sHs[128+b] + sHs[192+b] + sB[24];
          float z = fmaxf(sHz[b] + sHz[64+b] + sHz[128+b] + sHz[192+b] + sB[25], 0.f);
          if (wg < II) {
            size_t o = SF_OFF + ((size_t)b*DD + (q - TT))*II + wg;
            st_wt(&out[o], s);
          }
          stp(ZBP + ((size_t)(q&3) << 14) + ((((size_t)wg << 6) + b) << 1), z, (unsigned)(2*q+5));
        }
      }
    }
  }
}

extern "C" void kernel_launch(void* const* d_in, const int* in_sizes, int n_in,
                              void* d_out, int out_size, void* d_ws, size_t ws_size,
                              hipStream_t stream) {
  (void)in_sizes; (void)n_in; (void)out_size; (void)ws_size;
  qcm_kernel<<<dim3(NW), dim3(NTHR), 0, stream>>>(
      (const float*)d_in[0],
      (const float*)d_in[1], (const float*)d_in[2], (const float*)d_in[3],
      (const float*)d_in[4], (const float*)d_in[5], (const float*)d_in[6],
      (const float*)d_in[7], (const float*)d_in[8],
      (const float*)d_in[9], (const float*)d_in[10],
      (const float*)d_in[11], (const float*)d_in[12],
      (float*)d_out, (float*)d_ws);
}

// Round 8
// 14243.036 us; speedup vs baseline: 1.3680x; 1.3680x over previous
//
#include <hip/hip_runtime.h>
#include <math.h>

// ---------------------------------------------------------------------------
// QuantileCombinedModel — persistent-kernel LSTM encoder/decoder.
// R7: SEQLOCK v2 — single-epoch polling. R6's protocol (8B (value,seq) pairs,
// self-validating, no barriers/flags/fences) was correct but its chunked
// poll serialized 4-6 MALL round trips per phase. v2 issues ALL 64 pair
// loads of a matrix concurrently, FMA-consumes fragments as they verify,
// retries only stale ones. z-pair is loaded speculatively at phase start and
// verified late. Encoder x is read directly (lane=batch mapping + small LDS
// reduce) -> XT array eliminated, ws = 655 KB. Depth-2 slot buffering (every
// slot overwrite is gated on all readers having advanced - see seq analysis).
//   seq(h0[t]) = 2t+2  slot t&1     (init h0[-1]: seq 0, slot 1)
//   seq(h1[t]) = 2t+3  slot t&1     (init h1[-1]: seq 1, slot 1)
//   seq(z[q])  = 2q+5  slot q&1     (produced in phase B of tick q+1)
// Poison 0xAA never matches any expected seq. Arithmetic = R5/R6 (passed).
// ---------------------------------------------------------------------------

#define NW    128
#define NTHR  256

#define II 99
#define BB 64
#define TT 128
#define DD 325
#define QTOT 453
#define PPQ 9

#define SF_OFF 0
#define SB_OFF (BB*DD*II)            // 2059200
#define Y_OFF  (SB_OFF + BB*TT*II)   // 2870208

// ws float offsets — (value,seq) pair arrays, depth 2
#define WS_H0P 0                     // [2][256][64][2] = 65536 f
#define WS_H1P 65536                 // [2][256][64][2]
#define WS_ZBP 131072                // [2][128][64][2] = 32768 f  (total 655KB)

#define AGENT __HIP_MEMORY_SCOPE_AGENT

typedef float f4 __attribute__((ext_vector_type(4)));
typedef unsigned long long u64;

__device__ __forceinline__ float sigm(float v){ return 1.0f/(1.0f+expf(-v)); }
__device__ __forceinline__ void st_wt(float* p, float v){ __hip_atomic_store(p, v, __ATOMIC_RELAXED, AGENT); }
__device__ __forceinline__ void stp(float* p, float v, unsigned s){
  u64 u = ((u64)s << 32) | (u64)__float_as_uint(v);
  __hip_atomic_store((u64*)p, u, __ATOMIC_RELAXED, AGENT);
}
__device__ __forceinline__ u64 ald(const float* p){
  return __hip_atomic_load((const u64*)p, __ATOMIC_RELAXED, AGENT);
}

__device__ __forceinline__ void fma32(float acc[32], f4 w0, f4 w1, f4 hv) {
  float wr[8] = {w0.x,w0.y,w0.z,w0.w,w1.x,w1.y,w1.z,w1.w};
  #pragma unroll
  for (int g = 0; g < 8; ++g) {
    acc[(g<<2)+0] += wr[g]*hv.x;
    acc[(g<<2)+1] += wr[g]*hv.y;
    acc[(g<<2)+2] += wr[g]*hv.z;
    acc[(g<<2)+3] += wr[g]*hv.w;
  }
}

__global__ __launch_bounds__(NTHR, 1)
void qcm_kernel(const float* __restrict__ x,
                const float* __restrict__ Wih0, const float* __restrict__ Whh0, const float* __restrict__ b0,
                const float* __restrict__ Wih1, const float* __restrict__ Whh1, const float* __restrict__ b1,
                const float* __restrict__ Wlin, const float* __restrict__ blin,
                const float* __restrict__ Wp1,  const float* __restrict__ bp1,
                const float* __restrict__ Wp2,  const float* __restrict__ bp2,
                float* __restrict__ out, float* __restrict__ ws)
{
  // ---- LDS (~64 KB) ----
  __shared__ float sWih0[II*8];      // [k][g]
  __shared__ float sWhh0[2048];
  __shared__ float sWc  [2048];
  __shared__ float sWih1[2048];
  __shared__ float sWhh1[2048];
  __shared__ float sWlin[256];
  __shared__ float sWp1 [256];
  __shared__ float sWp2 [10*128];
  __shared__ float sGred[4*512];
  __shared__ float sGates[512];
  __shared__ float sXred[4*512];     // encoder x-projection partials [wv][g][b]
  __shared__ float sHs[4*64];
  __shared__ float sHz[4*64];
  __shared__ float sYred[2][8];
  __shared__ float sB[48];           // 0..7 b0 | 8..15 b0c | 16..23 b1 | 24 blin 25 bp1 | 32..40 bp2

  float* H0P = ws + WS_H0P;
  float* H1P = ws + WS_H1P;
  float* ZBP = ws + WS_ZBP;

  const int wg  = (int)blockIdx.x;
  const int tid = (int)threadIdx.x;
  const int wv  = tid >> 6;
  const int ln  = tid & 63;
  const int rg  = ln >> 2;
  const int rb  = rg << 2;              // batch base (4 per thread)
  const int ks  = (wv << 2) | (ln & 3); // k-sub 0..15
  const int u0  = wg << 1;

  float c0 = 0.f, c1 = 0.f;

  // single-epoch seqlock matrix read: issue all 64 pair-loads, consume valid
  // fragments immediately, retry only stale ones.
  auto pass16 = [&](const float* hb, unsigned exp, auto&& use) {
    const float* pb_ = hb + (((size_t)ks << 7) + ((size_t)rb << 1));
    u64 pr[16][4];
    #pragma unroll
    for (int j = 0; j < 16; ++j) {
      const float* p = pb_ + ((size_t)j << 11);
      pr[j][0]=ald(p); pr[j][1]=ald(p+2); pr[j][2]=ald(p+4); pr[j][3]=ald(p+6);
    }
    unsigned todo = 0;
    #pragma unroll
    for (int j = 0; j < 16; ++j) {
      bool ok = ((unsigned)(pr[j][0]>>32)==exp) && ((unsigned)(pr[j][1]>>32)==exp)
             && ((unsigned)(pr[j][2]>>32)==exp) && ((unsigned)(pr[j][3]>>32)==exp);
      if (ok) {
        f4 v; v.x=__uint_as_float((unsigned)pr[j][0]); v.y=__uint_as_float((unsigned)pr[j][1]);
              v.z=__uint_as_float((unsigned)pr[j][2]); v.w=__uint_as_float((unsigned)pr[j][3]);
        use(j, v);
      } else todo |= 1u << j;
    }
    while (todo) {
      __builtin_amdgcn_s_sleep(1);
      #pragma unroll
      for (int j = 0; j < 16; ++j) if ((todo >> j) & 1u) {
        const float* p = pb_ + ((size_t)j << 11);
        u64 a=ald(p), b2=ald(p+2), c2=ald(p+4), d2=ald(p+6);
        bool ok = ((unsigned)(a>>32)==exp) && ((unsigned)(b2>>32)==exp)
               && ((unsigned)(c2>>32)==exp) && ((unsigned)(d2>>32)==exp);
        if (ok) {
          f4 v; v.x=__uint_as_float((unsigned)a); v.y=__uint_as_float((unsigned)b2);
                v.z=__uint_as_float((unsigned)c2); v.w=__uint_as_float((unsigned)d2);
          use(j, v);
          todo &= ~(1u << j);
        }
      }
    }
  };

  // ======================= PROLOGUE =======================
  for (int idx = tid; idx < II*8; idx += NTHR) {
    int k = idx >> 3, g = idx & 7;
    int gate = ((g >> 1) << 8) + u0 + (g & 1);
    sWih0[idx] = Wih0[gate*II + k];
  }
  for (int idx = tid; idx < 2048; idx += NTHR) {
    int k = idx >> 3, g = idx & 7;
    int gate = ((g >> 1) << 8) + u0 + (g & 1);
    sWhh0[idx] = Whh0[(gate << 8) + k];
    sWih1[idx] = Wih1[(gate << 8) + k];
    sWhh1[idx] = Whh1[(gate << 8) + k];
  }
  sWlin[tid] = (wg < II) ? Wlin[wg*256 + tid] : 0.f;
  sWp1[tid]  = Wp1[wg*256 + tid];
  for (int idx = tid; idx < 1280; idx += NTHR) sWp2[idx] = (idx < 1152) ? Wp2[idx] : 0.f;
  if (tid < 8) {
    int gate = ((tid >> 1) << 8) + u0 + (tid & 1);
    sB[tid]      = b0[gate];
    sB[16 + tid] = b1[gate];
  }
  if (tid == 0) {
    sB[24] = (wg < II) ? blin[wg] : 0.f;
    sB[25] = bp1[wg];
  }
  if (tid < 9) sB[32 + tid] = bp2[tid];
  __syncthreads();
  // Wc slice: sWc[k*8+g] = sum_j Wih0[gate(g)][j] * Wlin[j][k]
  for (int idx = tid; idx < 2048; idx += NTHR) {
    int k = idx >> 3, g = idx & 7;
    float a = 0.f;
    for (int j = 0; j < II; ++j) a += sWih0[(j << 3) + g] * Wlin[(j << 8) + k];
    sWc[idx] = a;
  }
  if (tid < 8) {
    float a = 0.f;
    for (int j = 0; j < II; ++j) a += sWih0[(j << 3) + tid] * blin[j];
    sB[8 + tid] = sB[tid] + a;
  }
  // initial state pairs: h0[-1]=0 seq 0, h1[-1]=0 seq 1, slot (-1)&1 = 1
  if (tid < 128) {
    int uu = tid >> 6, r = tid & 63;
    stp(H0P + ((size_t)1 << 15) + ((((size_t)(u0+uu) << 6) + r) << 1), 0.f, 0u);
    stp(H1P + ((size_t)1 << 15) + ((((size_t)(u0+uu) << 6) + r) << 1), 0.f, 1u);
  }
  __syncthreads();

  const int bq = wg >> 1, pb2 = (wg & 1) ? 5 : 0;

  for (int ctr = 0; ctr <= 454; ++ctr) {
    // ========================= PHASE A (layer-0 step + yld head) =========================
    {
      // speculative z[ctr-2] pair load (verified late)
      u64 zu = 0; float* zp = nullptr; unsigned ez = 0;
      if (ctr >= 2 && tid < 128) {
        int q = ctr - 2;
        ez = (unsigned)(2*q + 5);
        zp = ZBP + ((size_t)(q & 1) << 14) + ((((size_t)tid << 6) + bq) << 1);
        zu = ald(zp);
      }
      if (ctr <= 452) {
        float acc[32];
        #pragma unroll
        for (int q2 = 0; q2 < 32; ++q2) acc[q2] = 0.f;

        if (ctr < TT) {
          // encoder x-projection: lane=batch, wave=k-quarter
          float ax[8];
          #pragma unroll
          for (int g = 0; g < 8; ++g) ax[g] = 0.f;
          const int kb = wv*25, kq = (wv < 3) ? 25 : 24;
          const float* xp = x + (size_t)ln*(TT*II) + (size_t)ctr*II + kb;
          #pragma unroll
          for (int i = 0; i < 25; ++i) if (i < kq) {
            float xv = xp[i];
            #pragma unroll
            for (int g = 0; g < 8; ++g) ax[g] += xv * sWih0[((kb+i) << 3) + g];
          }
          #pragma unroll
          for (int g = 0; g < 8; ++g) sXred[(wv << 9) + (g << 6) + ln] = ax[g];
          // + Whh0 @ h0[ctr-1]
          pass16(H0P + ((size_t)((ctr-1)&1) << 15), (unsigned)(2*ctr),
                 [&](int j, f4 v){ int k = ks + (j << 4);
                   fma32(acc, *(const f4*)(sWhh0 + (k<<3)), *(const f4*)(sWhh0 + (k<<3) + 4), v); });
        } else {
          // decoder: Whh0 @ h0[ctr-1] (older first) + Wc @ relu(h1[ctr-1])
          pass16(H0P + ((size_t)((ctr-1)&1) << 15), (unsigned)(2*ctr),
                 [&](int j, f4 v){ int k = ks + (j << 4);
                   fma32(acc, *(const f4*)(sWhh0 + (k<<3)), *(const f4*)(sWhh0 + (k<<3) + 4), v); });
          pass16(H1P + ((size_t)((ctr-1)&1) << 15), (unsigned)(2*ctr+1),
                 [&](int j, f4 v){ int k = ks + (j << 4);
                   v.x=fmaxf(v.x,0.f); v.y=fmaxf(v.y,0.f); v.z=fmaxf(v.z,0.f); v.w=fmaxf(v.w,0.f);
                   fma32(acc, *(const f4*)(sWc + (k<<3)), *(const f4*)(sWc + (k<<3) + 4), v); });
        }
        // gate partial reduce
        #pragma unroll
        for (int q2 = 0; q2 < 32; ++q2) {
          float v = acc[q2];
          v += __shfl_xor(v, 1, 64); v += __shfl_xor(v, 2, 64);
          acc[q2] = v;
        }
        if ((ln & 3) == 0) {
          #pragma unroll
          for (int g = 0; g < 8; ++g)
            *(float4*)(sGred + (wv << 9) + (g << 6) + rb) =
              make_float4(acc[(g<<2)], acc[(g<<2)+1], acc[(g<<2)+2], acc[(g<<2)+3]);
        }
      }
      // z verify + yld partials
      if (ctr >= 2 && tid < 128) {
        while ((unsigned)(zu >> 32) != ez) { __builtin_amdgcn_s_sleep(1); zu = ald(zp); }
        float zv = __uint_as_float((unsigned)zu);
        float yp[5];
        #pragma unroll
        for (int p = 0; p < 5; ++p) yp[p] = zv * sWp2[((pb2 + p) << 7) + tid];
        #pragma unroll
        for (int p = 0; p < 5; ++p) {
          float v = yp[p];
          v += __shfl_xor(v,1,64); v += __shfl_xor(v,2,64); v += __shfl_xor(v,4,64);
          v += __shfl_xor(v,8,64); v += __shfl_xor(v,16,64); v += __shfl_xor(v,32,64);
          yp[p] = v;
        }
        if (ln == 0) {
          #pragma unroll
          for (int p = 0; p < 5; ++p) sYred[wv][p] = yp[p];
        }
      }
      __syncthreads();
      if (ctr <= 452 && tid < 128) { // gate final sum + bias (+ x partials in encoder)
        const int boff = (ctr < TT) ? 0 : 8;
        const int g = tid >> 4, bb = (tid & 15) << 2;
        float4 a0 = *(const float4*)(sGred +    0 + (tid<<2));
        float4 a1 = *(const float4*)(sGred +  512 + (tid<<2));
        float4 a2 = *(const float4*)(sGred + 1024 + (tid<<2));
        float4 a3 = *(const float4*)(sGred + 1536 + (tid<<2));
        float bias = sB[boff + g];
        float4 r;
        r.x = a0.x+a1.x+a2.x+a3.x + bias;
        r.y = a0.y+a1.y+a2.y+a3.y + bias;
        r.z = a0.z+a1.z+a2.z+a3.z + bias;
        r.w = a0.w+a1.w+a2.w+a3.w + bias;
        if (ctr < TT) {
          #pragma unroll
          for (int w2 = 0; w2 < 4; ++w2) {
            float4 xr = *(const float4*)(sXred + (w2 << 9) + (g << 6) + bb);
            r.x += xr.x; r.y += xr.y; r.z += xr.z; r.w += xr.w;
          }
        }
        *(float4*)(sGates + (tid<<2)) = r;
      }
      if (ctr >= 2 && tid >= 192 && tid < 197) {
        int p = tid - 192;
        if (pb2 + p < 9) {
          float y = sYred[0][p] + sYred[1][p] + sB[32 + pb2 + p];
          st_wt(&out[Y_OFF + ((size_t)bq*QTOT + (ctr - 2))*PPQ + pb2 + p], y);
        }
      }
      __syncthreads();
      if (ctr <= 452 && tid < 128) { // LSTM cell, layer 0 -> pair store seq 2ctr+2 slot ctr&1
        int uu = tid >> 6, r = tid & 63;
        float i_ = sigm (sGates[( uu      << 6) + r]);
        float f_ = sigm (sGates[((2 + uu) << 6) + r]);
        float g_ = tanhf(sGates[((4 + uu) << 6) + r]);
        float o_ = sigm (sGates[((6 + uu) << 6) + r]);
        float c = f_*c0 + i_*g_;
        c0 = c;
        stp(H0P + ((size_t)(ctr&1) << 15) + ((((size_t)(u0+uu) << 6) + r) << 1),
            o_*tanhf(c), (unsigned)(2*ctr+2));
      }
    }
    if (ctr == 454) break;

    // ========================= PHASE B (layer-1 step + sens/z heads) =========================
    {
      float ps4[4] = {0,0,0,0}, pz4[4] = {0,0,0,0};
      if (ctr <= 452) {
        float acc[32];
        #pragma unroll
        for (int q2 = 0; q2 < 32; ++q2) acc[q2] = 0.f;

        // Whh1 @ h1[ctr-1] + head partials (older data, first)
        pass16(H1P + ((size_t)((ctr-1)&1) << 15), (unsigned)(2*ctr+1),
               [&](int j, f4 v){ int k = ks + (j << 4);
                 fma32(acc, *(const f4*)(sWhh1 + (k<<3)), *(const f4*)(sWhh1 + (k<<3) + 4), v);
                 float rx=fmaxf(v.x,0.f), ry=fmaxf(v.y,0.f), rz=fmaxf(v.z,0.f), rw=fmaxf(v.w,0.f);
                 float wl = sWlin[k], wp = sWp1[k];
                 ps4[0]+=rx*wl; ps4[1]+=ry*wl; ps4[2]+=rz*wl; ps4[3]+=rw*wl;
                 pz4[0]+=rx*wp; pz4[1]+=ry*wp; pz4[2]+=rz*wp; pz4[3]+=rw*wp; });
        // Wih1 @ h0[ctr] (fresh, second)
        pass16(H0P + ((size_t)(ctr&1) << 15), (unsigned)(2*ctr+2),
               [&](int j, f4 v){ int k = ks + (j << 4);
                 fma32(acc, *(const f4*)(sWih1 + (k<<3)), *(const f4*)(sWih1 + (k<<3) + 4), v); });

        #pragma unroll
        for (int q2 = 0; q2 < 32; ++q2) {
          float v = acc[q2];
          v += __shfl_xor(v, 1, 64); v += __shfl_xor(v, 2, 64);
          acc[q2] = v;
        }
        #pragma unroll
        for (int j = 0; j < 4; ++j) {
          float v = ps4[j]; v += __shfl_xor(v,1,64); v += __shfl_xor(v,2,64); ps4[j] = v;
          v = pz4[j]; v += __shfl_xor(v,1,64); v += __shfl_xor(v,2,64); pz4[j] = v;
        }
        if ((ln & 3) == 0) {
          #pragma unroll
          for (int g = 0; g < 8; ++g)
            *(float4*)(sGred + (wv << 9) + (g << 6) + rb) =
              make_float4(acc[(g<<2)], acc[(g<<2)+1], acc[(g<<2)+2], acc[(g<<2)+3]);
          *(float4*)(sHs + (wv << 6) + rb) = make_float4(ps4[0],ps4[1],ps4[2],ps4[3]);
          *(float4*)(sHz + (wv << 6) + rb) = make_float4(pz4[0],pz4[1],pz4[2],pz4[3]);
        }
        __syncthreads();
        if (tid < 128) {
          float4 a0 = *(const float4*)(sGred +    0 + (tid<<2));
          float4 a1 = *(const float4*)(sGred +  512 + (tid<<2));
          float4 a2 = *(const float4*)(sGred + 1024 + (tid<<2));
          float4 a3 = *(const float4*)(sGred + 1536 + (tid<<2));
          float bias = sB[16 + (tid >> 4)];
          float4 r;
          r.x = a0.x+a1.x+a2.x+a3.x + bias;
          r.y = a0.y+a1.y+a2.y+a3.y + bias;
          r.z = a0.z+a1.z+a2.z+a3.z + bias;
          r.w = a0.w+a1.w+a2.w+a3.w + bias;
          *(float4*)(sGates + (tid<<2)) = r;
        } else if (tid < 192 && ctr >= 1) { // sens/z finalize, q = ctr-1
          int b = tid - 128, q = ctr - 1;
          float s = sHs[b] + sHs[64+b] + sHs[128+b] + sHs[192+b] + sB[24];
          float z = fmaxf(sHz[b] + sHz[64+b] + sHz[128+b] + sHz[192+b] + sB[25], 0.f);
          if (wg < II) {
            size_t o = (q < TT) ? (SB_OFF + ((size_t)b*TT + q)*II + wg)
                                : (SF_OFF + ((size_t)b*DD + (q - TT))*II + wg);
            st_wt(&out[o], s);
          }
          stp(ZBP + ((size_t)(q&1) << 14) + ((((size_t)wg << 6) + b) << 1), z, (unsigned)(2*q+5));
        }
        __syncthreads();
        if (tid < 128) { // LSTM cell, layer 1 -> pair store seq 2ctr+3 slot ctr&1
          int uu = tid >> 6, r = tid & 63;
          float i_ = sigm (sGates[( uu      << 6) + r]);
          float f_ = sigm (sGates[((2 + uu) << 6) + r]);
          float g_ = tanhf(sGates[((4 + uu) << 6) + r]);
          float o_ = sigm (sGates[((6 + uu) << 6) + r]);
          float c = f_*c1 + i_*g_;
          c1 = c;
          stp(H1P + ((size_t)(ctr&1) << 15) + ((((size_t)(u0+uu) << 6) + r) << 1),
              o_*tanhf(c), (unsigned)(2*ctr+3));
        }
      } else { // ctr == 453: heads only from h1[452]
        pass16(H1P + ((size_t)((ctr-1)&1) << 15), (unsigned)(2*ctr+1),
               [&](int j, f4 v){ int k = ks + (j << 4);
                 float rx=fmaxf(v.x,0.f), ry=fmaxf(v.y,0.f), rz=fmaxf(v.z,0.f), rw=fmaxf(v.w,0.f);
                 float wl = sWlin[k], wp = sWp1[k];
                 ps4[0]+=rx*wl; ps4[1]+=ry*wl; ps4[2]+=rz*wl; ps4[3]+=rw*wl;
                 pz4[0]+=rx*wp; pz4[1]+=ry*wp; pz4[2]+=rz*wp; pz4[3]+=rw*wp; });
        #pragma unroll
        for (int j = 0; j < 4; ++j) {
          float v = ps4[j]; v += __shfl_xor(v,1,64); v += __shfl_xor(v,2,64); ps4[j] = v;
          v = pz4[j]; v += __shfl_xor(v,1,64); v += __shfl_xor(v,2,64); pz4[j] = v;
        }
        if ((ln & 3) == 0) {
          *(float4*)(sHs + (wv << 6) + rb) = make_float4(ps4[0],ps4[1],ps4[2],ps4[3]);
          *(float4*)(sHz + (wv << 6) + rb) = make_float4(pz4[0],pz4[1],pz4[2],pz4[3]);
        }
        __syncthreads();
        if (tid >= 128 && tid < 192) {
          int b = tid - 128, q = ctr - 1;
          float s = sHs[b] + sHs[64+b] + sHs[128+b] + sHs[192+b] + sB[24];
          float z = fmaxf(sHz[b] + sHz[64+b] + sHz[128+b] + sHz[192+b] + sB[25], 0.f);
          if (wg < II) {
            size_t o = SF_OFF + ((size_t)b*DD + (q - TT))*II + wg;
            st_wt(&out[o], s);
          }
          stp(ZBP + ((size_t)(q&1) << 14) + ((((size_t)wg << 6) + b) << 1), z, (unsigned)(2*q+5));
        }
        __syncthreads();
      }
    }
  }
}

extern "C" void kernel_launch(void* const* d_in, const int* in_sizes, int n_in,
                              void* d_out, int out_size, void* d_ws, size_t ws_size,
                              hipStream_t stream) {
  (void)in_sizes; (void)n_in; (void)out_size; (void)ws_size;
  qcm_kernel<<<dim3(NW), dim3(NTHR), 0, stream>>>(
      (const float*)d_in[0],
      (const float*)d_in[1], (const float*)d_in[2], (const float*)d_in[3],
      (const float*)d_in[4], (const float*)d_in[5], (const float*)d_in[6],
      (const float*)d_in[7], (const float*)d_in[8],
      (const float*)d_in[9], (const float*)d_in[10],
      (const float*)d_in[11], (const float*)d_in[12],
      (float*)d_out, (float*)d_ws);
}